// Round 8
// baseline (462.565 us; speedup 1.0000x reference)
//
#include <hip/hip_runtime.h>

typedef int v4i  __attribute__((ext_vector_type(4)));
typedef int v16i __attribute__((ext_vector_type(16)));

__device__ __forceinline__ int pack4i(int a, int b, int c, int d) {
  return (a & 255) | ((b & 255) << 8) | ((c & 255) << 16) | ((d & 255) << 24);
}
// SWAR per-byte add (mod-256 per lane-byte)
__device__ __forceinline__ int badd4(int a, int b) {
  return ((a & 0x7f7f7f7f) + (b & 0x7f7f7f7f)) ^ ((a ^ b) & 0x80808080);
}

#define MFMA_I8(a, b, c) __builtin_amdgcn_mfma_i32_32x32x32_i8(a, b, c, 0, 0, 0)
// Counted waits + raw barrier (R5-R7-verified): __syncthreads would drain
// vmcnt to 0 and kill the pipeline. BARX orders ds ops then syncs.
#define WAITV(N) asm volatile("s_waitcnt vmcnt(" #N ")" ::: "memory")
#define BARX do { asm volatile("s_waitcnt lgkmcnt(0)" ::: "memory"); \
                  __builtin_amdgcn_s_barrier(); } while (0)

// ---------------------------------------------------------------------------
// Pack (W + E) -> int8, transposed Bt[n][k] (row stride K bytes).
// ---------------------------------------------------------------------------
__device__ void pack_tile(const int* __restrict__ W, const int* __restrict__ E,
                          char* __restrict__ Bt, int K, int N,
                          int nx, int ky, char* lin) {
  const int t = threadIdx.x;
  const int n0 = nx * 64, k0 = ky * 256;
  {
    const int c  = t & 15;          // column group: 4 ints = 16 B
    const int kq = t >> 4;          // 0..15
    const int ng = n0 + c * 4;
    #pragma unroll 4
    for (int s = 0; s < 16; ++s) {
      const int k = s * 16 + kq;
      const long grow = (long)(k0 + k) * N;
      int a0, a1, a2, a3;
      if (ng + 3 < N) {
        int4 wv = *(const int4*)(W + grow + ng);
        int4 ev = *(const int4*)(E + grow + ng);
        a0 = wv.x + ev.x; a1 = wv.y + ev.y; a2 = wv.z + ev.z; a3 = wv.w + ev.w;
      } else {
        a0 = (ng + 0 < N) ? W[grow + ng + 0] + E[grow + ng + 0] : 0;
        a1 = (ng + 1 < N) ? W[grow + ng + 1] + E[grow + ng + 1] : 0;
        a2 = (ng + 2 < N) ? W[grow + ng + 2] + E[grow + ng + 2] : 0;
        a3 = (ng + 3 < N) ? W[grow + ng + 3] + E[grow + ng + 3] : 0;
      }
      *(int*)(lin + k * 68 + c * 4) = pack4i(a0, a1, a2, a3);
    }
  }
  __syncthreads();
  {
    const int n = t & 63, kq = t >> 6;
    char* dst = Bt + (long)(n0 + n) * K + k0 + (kq << 6);
    int outv[16];
    #pragma unroll
    for (int g = 0; g < 16; ++g) {
      const int k = (kq << 6) + (g << 2);
      outv[g] = pack4i(lin[(k + 0) * 68 + n], lin[(k + 1) * 68 + n],
                       lin[(k + 2) * 68 + n], lin[(k + 3) * 68 + n]);
    }
    #pragma unroll
    for (int g = 0; g < 4; ++g)
      *(int4*)(dst + (g << 4)) =
          make_int4(outv[g * 4], outv[g * 4 + 1], outv[g * 4 + 2], outv[g * 4 + 3]);
  }
}

__global__ __launch_bounds__(256) void pack_weights_kernel(
    const int* W1, const int* E1, char* Bt1,
    const int* W2, const int* E2, char* Bt2,
    const int* W3, const int* E3, char* Bt3,
    const int* b1, const int* eb1, int* bs1,
    const int* b2, const int* eb2, int* bs2,
    const int* b3, const int* eb3, int* bs3) {
  __shared__ __align__(16) char smem[17408];
  const int bid = blockIdx.x;
  if (bid < 192) {
    pack_tile(W1, E1, Bt1, 3072, 1024, bid % 16, bid / 16, smem);
  } else if (bid < 256) {
    const int l = bid - 192;
    pack_tile(W2, E2, Bt2, 1024, 1024, l % 16, l / 16, smem);
  } else if (bid < 264) {
    const int l = bid - 256;
    pack_tile(W3, E3, Bt3, 1024, 100, l & 1, l >> 1, smem);
  } else {
    const int t = threadIdx.x;
    for (int i = t; i < 1024; i += 256) {
      bs1[i] = b1[i] + eb1[i];
      bs2[i] = b2[i] + eb2[i];
    }
    for (int i = t; i < 128; i += 256)
      bs3[i] = (i < 100) ? (b3[i] + eb3[i]) : 0;
  }
}

// ---------------------------------------------------------------------------
// R8 gemm1: 64x256 tile (BN 128->256: the ONE structural change). R7 math:
// at BN=128 X is re-read 8x = 805 MB logical -> ~10.6 TB/s through L2/L3 =
// the Infinity-Cache wall (FETCH was already ideal; WAITV stalls measured
// ~2400cy effective latency = queueing). BN=256 halves X logical to 402 MB.
// 4 waves (1x4, each 64x64), BK=64, grid 512 = 128mt x 4nt (2 blk/CU;
// bid&127=mt, 128%8==0 -> nt-sharers of an A-panel co-XCD).
// 2-stage LDS (A 64x80 + B 256x80 = 25600/stage; x2 = 51200 -> 3-stage
// doesn't fit 64 KB), so TWO barriers per K-step; counted-vmcnt depth-2
// pipeline kept: 8 loads/thread/step (4 A-int4 + 4 B-int4) -> WAITV(8).
// Lane-contiguous maps (R7): A: 16 thr x 16 B cover a 256 B row-slice;
// B: 4 thr x 16 B cover a 64 B row-slice.
// ---------------------------------------------------------------------------
__global__ __launch_bounds__(256, 2) void gemm1_kernel(
    const int* __restrict__ X, const char* __restrict__ Btg,
    const int* __restrict__ bsum, const int* __restrict__ H,
    char* __restrict__ A8out) {
  constexpr int K = 3072, KIT = 48;
  __shared__ __align__(16) char smem[51200];
  const int t = threadIdx.x;
  const int bid = blockIdx.x;
  const int mt = bid & 127, nt = bid >> 7;
  const long m0 = (long)mt << 6;
  const int n0 = nt << 8;

  const int lane = t & 63, wn = t >> 6;       // wave wn owns cols wn*64..+63
  const int lc = lane & 31, hg = lane >> 5;

  v16i acc[2][2] = {};   // [i: row half 0/32][j: col half 0/32]

  // A staging: rows (t>>4)+16j (j=0..3), 16 B chunk (t&15)*16 of 256 B slice
  const int ar16 = t >> 4, ac = t & 15;
  const int* Xbase = X + (m0 + ar16) * (long)K + ac * 4;
  const int awo = ar16 * 80 + ac * 4;
  // B staging: rows (t>>2)+64j (j=0..3), 16 B chunk (t&3)*16 of 64 B slice
  const int br4 = t >> 2, bc = t & 3;
  const char* Bbase = Btg + (long)(n0 + br4) * K + bc * 16;
  const int bwo = 5120 + br4 * 80 + bc * 16;

  // fragment bases (80 B stride)
  const int fa = lc * 80;
  const int fb = 5120 + (wn * 64 + lc) * 80;

  int4 xA[4], yA[4], xB[4], yB[4];            // named depth-2 prefetch sets

#define G1_ISSUE(PA, PB, kt) do {                                   \
    const int ko_ = (kt) * 64;                                      \
    _Pragma("unroll")                                               \
    for (int j = 0; j < 4; ++j)                                     \
      PA[j] = *(const int4*)(Xbase + (long)j * 16 * K + ko_);       \
    _Pragma("unroll")                                               \
    for (int j = 0; j < 4; ++j)                                     \
      PB[j] = *(const int4*)(Bbase + (long)j * 64 * K + ko_);       \
  } while (0)
#define G1_WRITE(PA, PB, st) do {                                   \
    char* base_ = smem + (st) * 25600;                              \
    _Pragma("unroll")                                               \
    for (int j = 0; j < 4; ++j)                                     \
      *(int*)(base_ + awo + j * 16 * 80) =                          \
          pack4i(PA[j].x, PA[j].y, PA[j].z, PA[j].w);               \
    _Pragma("unroll")                                               \
    for (int j = 0; j < 4; ++j)                                     \
      *(int4*)(base_ + bwo + j * 64 * 80) = PB[j];                  \
  } while (0)

  auto MSTEP = [&](int st) {
    const char* base = smem + st * 25600;
    __builtin_amdgcn_s_setprio(1);
    #pragma unroll
    for (int ks = 0; ks < 2; ++ks) {
      const int sel = ks * 32 + hg * 16;
      v4i a0 = *(const v4i*)(base + fa + sel);
      v4i a1 = *(const v4i*)(base + fa + 32 * 80 + sel);
      v4i b0 = *(const v4i*)(base + fb + sel);
      v4i b1 = *(const v4i*)(base + fb + 32 * 80 + sel);
      acc[0][0] = MFMA_I8(a0, b0, acc[0][0]);
      acc[0][1] = MFMA_I8(a0, b1, acc[0][1]);
      acc[1][0] = MFMA_I8(a1, b0, acc[1][0]);
      acc[1][1] = MFMA_I8(a1, b1, acc[1][1]);
    }
    __builtin_amdgcn_s_setprio(0);
  };

  // Prologue: sets 0 (X) and 1 (Y) in flight; write 0; sync.
  G1_ISSUE(xA, xB, 0);
  G1_ISSUE(yA, yB, 1);
  WAITV(8);                     // set 0 landed (set 1's 8 outstanding)
  G1_WRITE(xA, xB, 0);
  BARX;

  for (int kt = 0; kt < KIT; kt += 2) {
    // even step kt: compute stage kt&1; stage (kt+1)&1 written from Y
    if (kt + 2 < KIT) G1_ISSUE(xA, xB, kt + 2);
    MSTEP(kt & 1);
    if (kt + 2 < KIT) WAITV(8); else WAITV(0);   // set kt+1 landed
    BARX;                        // all waves done reading stage (kt+1)&1
    G1_WRITE(yA, yB, (kt + 1) & 1);
    BARX;                        // writes visible for MSTEP(kt+1)
    // odd step kt+1
    if (kt + 3 < KIT) G1_ISSUE(yA, yB, kt + 3);
    MSTEP((kt + 1) & 1);
    if (kt + 2 < KIT) {
      if (kt + 3 < KIT) WAITV(8); else WAITV(0); // set kt+2 landed
      BARX;
      G1_WRITE(xA, xB, (kt + 2) & 1);
      BARX;
    }
  }

  // Epilogue: LDS transpose (64 x stride 264) + SWAR-add trunc8(H int32).
  BARX;
  const int bsv0 = bsum[n0 + wn * 64 + lc];
  const int bsv1 = bsum[n0 + wn * 64 + 32 + lc];
  #pragma unroll
  for (int i = 0; i < 2; ++i) {
    #pragma unroll
    for (int j = 0; j < 2; ++j) {
      const int bv = j ? bsv1 : bsv0;
      const int col = wn * 64 + j * 32 + lc;
      #pragma unroll
      for (int rr = 0; rr < 16; ++rr) {
        const int row = i * 32 + (hg << 2) + (rr & 3) + ((rr >> 2) << 3);
        smem[row * 264 + col] = (char)(acc[i][j][rr] + bv);
      }
    }
  }
  BARX;
  // readout: thread -> row t>>2, 64 B seg (t&3)*64 of the 256-col tile
  const char* srcp = smem + (t >> 2) * 264 + (t & 3) * 64;
  const long gco = (m0 + (t >> 2)) * 1024 + n0 + (t & 3) * 64;
  const int* hp = H + gco;
  #pragma unroll
  for (int g = 0; g < 4; ++g) {
    int4 s  = *(const int4*)(srcp + g * 16);
    int4 h0 = *(const int4*)(hp + g * 16);
    int4 h1 = *(const int4*)(hp + g * 16 + 4);
    int4 h2 = *(const int4*)(hp + g * 16 + 8);
    int4 h3 = *(const int4*)(hp + g * 16 + 12);
    s = make_int4(badd4(s.x, pack4i(h0.x, h0.y, h0.z, h0.w)),
                  badd4(s.y, pack4i(h1.x, h1.y, h1.z, h1.w)),
                  badd4(s.z, pack4i(h2.x, h2.y, h2.z, h2.w)),
                  badd4(s.w, pack4i(h3.x, h3.y, h3.z, h3.w)));
    *(int4*)(A8out + gco + g * 16) = s;
  }
}

// ---------------------------------------------------------------------------
// R8 gemm2: same 64x256 template, A already int8 (1 A-load + 4 B-loads per
// thread per step -> WAITV(5)). K=1024, 16 steps. Direct int32 epilogue.
// ---------------------------------------------------------------------------
__global__ __launch_bounds__(256, 2) void gemm2_kernel(
    const char* __restrict__ A, const char* __restrict__ Btg,
    const int* __restrict__ bsum, int* __restrict__ Iout) {
  constexpr int K = 1024, KIT = 16;
  __shared__ __align__(16) char smem[51200];
  const int t = threadIdx.x;
  const int bid = blockIdx.x;
  const int mt = bid & 127, nt = bid >> 7;
  const long m0 = (long)mt << 6;
  const int n0 = nt << 8;

  const int lane = t & 63, wn = t >> 6;
  const int lc = lane & 31, hg = lane >> 5;

  v16i acc[2][2] = {};

  // A staging: row t>>2, 16 B chunk (t&3)*16 (4 thr x 16 B = 64 B row slice)
  const int ar4 = t >> 2, ac4 = t & 3;
  const char* Abase = A + (m0 + ar4) * (long)K + ac4 * 16;
  const int awo = ar4 * 80 + ac4 * 16;
  // B staging: rows (t>>2)+64j, chunk (t&3)*16
  const char* Bbase = Btg + (long)(n0 + ar4) * K + ac4 * 16;
  const int bwo = 5120 + ar4 * 80 + ac4 * 16;

  const int fa = lc * 80;
  const int fb = 5120 + (wn * 64 + lc) * 80;

  int4 xA0, yA0, xB[4], yB[4];

#define G2_ISSUE(PA, PB, kt) do {                                   \
    const int ko_ = (kt) * 64;                                      \
    PA = *(const int4*)(Abase + ko_);                               \
    _Pragma("unroll")                                               \
    for (int j = 0; j < 4; ++j)                                     \
      PB[j] = *(const int4*)(Bbase + (long)j * 64 * K + ko_);       \
  } while (0)
#define G2_WRITE(PA, PB, st) do {                                   \
    char* base_ = smem + (st) * 25600;                              \
    *(int4*)(base_ + awo) = PA;                                     \
    _Pragma("unroll")                                               \
    for (int j = 0; j < 4; ++j)                                     \
      *(int4*)(base_ + bwo + j * 64 * 80) = PB[j];                  \
  } while (0)

  auto MSTEP = [&](int st) {
    const char* base = smem + st * 25600;
    __builtin_amdgcn_s_setprio(1);
    #pragma unroll
    for (int ks = 0; ks < 2; ++ks) {
      const int sel = ks * 32 + hg * 16;
      v4i a0 = *(const v4i*)(base + fa + sel);
      v4i a1 = *(const v4i*)(base + fa + 32 * 80 + sel);
      v4i b0 = *(const v4i*)(base + fb + sel);
      v4i b1 = *(const v4i*)(base + fb + 32 * 80 + sel);
      acc[0][0] = MFMA_I8(a0, b0, acc[0][0]);
      acc[0][1] = MFMA_I8(a0, b1, acc[0][1]);
      acc[1][0] = MFMA_I8(a1, b0, acc[1][0]);
      acc[1][1] = MFMA_I8(a1, b1, acc[1][1]);
    }
    __builtin_amdgcn_s_setprio(0);
  };

  G2_ISSUE(xA0, xB, 0);
  G2_ISSUE(yA0, yB, 1);
  WAITV(5);
  G2_WRITE(xA0, xB, 0);
  BARX;

  for (int kt = 0; kt < KIT; kt += 2) {
    if (kt + 2 < KIT) G2_ISSUE(xA0, xB, kt + 2);
    MSTEP(kt & 1);
    if (kt + 2 < KIT) WAITV(5); else WAITV(0);
    BARX;
    G2_WRITE(yA0, yB, (kt + 1) & 1);
    BARX;
    if (kt + 3 < KIT) G2_ISSUE(yA0, yB, kt + 3);
    MSTEP((kt + 1) & 1);
    if (kt + 2 < KIT) {
      if (kt + 3 < KIT) WAITV(5); else WAITV(0);
      BARX;
      G2_WRITE(xA0, xB, (kt + 2) & 1);
      BARX;
    }
  }

  const int bsj0 = bsum[n0 + wn * 64 + lc];
  const int bsj1 = bsum[n0 + wn * 64 + 32 + lc];
  #pragma unroll
  for (int i = 0; i < 2; ++i) {
    #pragma unroll
    for (int j = 0; j < 2; ++j) {
      const int bv = j ? bsj1 : bsj0;
      const int col = n0 + wn * 64 + j * 32 + lc;
      #pragma unroll
      for (int rr = 0; rr < 16; ++rr) {
        const long row = m0 + i * 32 + (hg << 2) + (rr & 3) + ((rr >> 2) << 3);
        Iout[row * 1024 + col] = (int)(signed char)(acc[i][j][rr] + bv);
      }
    }
  }
}

// ---------------------------------------------------------------------------
// Layer 3: 16x128 tile, 512 blocks (2/CU), mfma_i32_16x16x64_i8, 2-stage.
// A = h2 int32 from d_out, packed to int8 in staging. (Long-verified.)
// ---------------------------------------------------------------------------
__global__ __launch_bounds__(256, 2) void gemm3_kernel(
    const int* __restrict__ h2, const char* __restrict__ Btg,
    const int* __restrict__ bsum, int* __restrict__ Iout) {
  // stage: As 16x80 (1280) + Bs 128x80 (10240) = 11520; x2 = 23040
  __shared__ __align__(16) char smem[23040];
  const int t = threadIdx.x;
  const int m0 = blockIdx.x << 4;
  const int lane = t & 63, w = t >> 6;
  const int l16 = lane & 15, q = lane >> 4;
  v4i acc0 = {}, acc1 = {};

  const int am = t >> 4, ah = t & 15;      // 16 rows x 16 thr x 4 ints
  const int* Arow = h2 + (long)(m0 + am) * 1024 + ah * 4;
  const int aoff = am * 80 + ah * 4;
  const int bm = t >> 1, bh = t & 1;       // 128 rows x 2 thr x 32 B
  const char* Brow = Btg + (long)bm * 1024 + bh * 32;
  const int boff = bm * 80 + bh * 32;

  const int abo  = l16 * 80 + q * 16;
  const int bbo0 = (w * 32 + l16) * 80 + q * 16;
  const int bbo1 = (w * 32 + 16 + l16) * 80 + q * 16;

  int4 ar, br0, br1;
  auto LOAD = [&](int kt) {
    const int kb = kt << 6;
    ar  = *(const int4*)(Arow + kb);
    br0 = *(const int4*)(Brow + kb);
    br1 = *(const int4*)(Brow + kb + 16);
  };
  auto STORE = [&](int stage) {
    char* base = smem + stage * 11520;
    *(int*)(base + aoff) = pack4i(ar.x, ar.y, ar.z, ar.w);
    *(int4*)(base + 1280 + boff)      = br0;
    *(int4*)(base + 1280 + boff + 16) = br1;
  };
  auto MFMA = [&](int stage) {
    const char* base = smem + stage * 11520;
    v4i a  = *(const v4i*)(base + abo);
    v4i b0 = *(const v4i*)(base + 1280 + bbo0);
    v4i b1 = *(const v4i*)(base + 1280 + bbo1);
    acc0 = __builtin_amdgcn_mfma_i32_16x16x64_i8(a, b0, acc0, 0, 0, 0);
    acc1 = __builtin_amdgcn_mfma_i32_16x16x64_i8(a, b1, acc1, 0, 0, 0);
  };

  LOAD(0); STORE(0); __syncthreads();
  for (int kt = 0; kt < 16; ++kt) {
    if (kt + 1 < 16) LOAD(kt + 1);
    MFMA(kt & 1);
    if (kt + 1 < 16) { STORE((kt + 1) & 1); __syncthreads(); }
  }

  const int c0 = w * 32 + l16;       // cols {0-15,32-47,64-79,96-111}
  const int c1 = c0 + 16;            // cols {16-31,48-63,80-95,112-127}
  if (c0 < 100) {
    const int b = bsum[c0];
    #pragma unroll
    for (int rr = 0; rr < 4; ++rr)
      Iout[(long)(m0 + q * 4 + rr) * 100 + c0] = (int)(signed char)(acc0[rr] + b);
  }
  if (c1 < 100) {
    const int b = bsum[c1];
    #pragma unroll
    for (int rr = 0; rr < 4; ++rr)
      Iout[(long)(m0 + q * 4 + rr) * 100 + c1] = (int)(signed char)(acc1[rr] + b);
  }
}

// ---------------------------------------------------------------------------
// ws (12.7 MB): Bt1 | Bt2 | Bt3 | bs1 | bs2 | bs3 | A2
// ---------------------------------------------------------------------------
extern "C" void kernel_launch(void* const* d_in, const int* in_sizes, int n_in,
                              void* d_out, int out_size, void* d_ws, size_t ws_size,
                              hipStream_t stream) {
  (void)in_sizes; (void)n_in; (void)out_size; (void)ws_size;
  const int* W1  = (const int*)d_in[0];
  const int* b1  = (const int*)d_in[1];
  const int* W2  = (const int*)d_in[2];
  const int* b2  = (const int*)d_in[3];
  const int* W3  = (const int*)d_in[4];
  const int* b3  = (const int*)d_in[5];
  const int* E1  = (const int*)d_in[6];
  const int* eb1 = (const int*)d_in[7];
  const int* E2  = (const int*)d_in[8];
  const int* eb2 = (const int*)d_in[9];
  const int* E3  = (const int*)d_in[10];
  const int* eb3 = (const int*)d_in[11];
  const int* X   = (const int*)d_in[12];   // [8192][3072] int32
  const int* H   = (const int*)d_in[13];   // [8192][1024] int32
  int* out = (int*)d_out;                  // h2 [8192*1024] then out [8192*100]

  char* ws  = (char*)d_ws;
  char* Bt1 = ws;                          // 3,145,728
  char* Bt2 = Bt1 + 3145728;               // 1,048,576
  char* Bt3 = Bt2 + 1048576;               //   131,072 (rows 100..127 zeroed)
  int*  bs1 = (int*)(Bt3 + 131072);        // 1024 ints
  int*  bs2 = bs1 + 1024;                  // 1024 ints
  int*  bs3 = bs2 + 1024;                  //  128 ints
  char* A2  = (char*)(bs3 + 128);          // 8,388,608 int8

  pack_weights_kernel<<<dim3(265), dim3(256), 0, stream>>>(
      W1, E1, Bt1, W2, E2, Bt2, W3, E3, Bt3,
      b1, eb1, bs1, b2, eb2, bs2, b3, eb3, bs3);

  // Layer 1: X (int32, fused pack) -> i2c ; epilogue adds trunc8(H) -> A2
  gemm1_kernel<<<dim3(512), dim3(256), 0, stream>>>(X, Bt1, bs1, H, A2);

  // Layer 2: h2 -> d_out (int32)
  gemm2_kernel<<<dim3(512), dim3(256), 0, stream>>>(A2, Bt2, bs2, out);

  // Layer 3: reads h2 from d_out (int32), writes out region (int32)
  gemm3_kernel<<<dim3(512), dim3(256), 0, stream>>>(
      out, Bt3, bs3, out + 8388608);
}

// Round 9
// 292.184 us; speedup vs baseline: 1.5831x; 1.5831x over previous
//
#include <hip/hip_runtime.h>

typedef int v4i  __attribute__((ext_vector_type(4)));
typedef int v16i __attribute__((ext_vector_type(16)));

__device__ __forceinline__ int pack4i(int a, int b, int c, int d) {
  return (a & 255) | ((b & 255) << 8) | ((c & 255) << 16) | ((d & 255) << 24);
}
// SWAR per-byte add (mod-256 per lane-byte)
__device__ __forceinline__ int badd4(int a, int b) {
  return ((a & 0x7f7f7f7f) + (b & 0x7f7f7f7f)) ^ ((a ^ b) & 0x80808080);
}

#define MFMA_I8(a, b, c) __builtin_amdgcn_mfma_i32_32x32x32_i8(a, b, c, 0, 0, 0)
// Counted waits + raw barrier (R5-R7-verified): __syncthreads would drain
// vmcnt to 0 and kill the pipeline. BARX orders ds ops then syncs.
#define WAITV(N) asm volatile("s_waitcnt vmcnt(" #N ")" ::: "memory")
#define BARX do { asm volatile("s_waitcnt lgkmcnt(0)" ::: "memory"); \
                  __builtin_amdgcn_s_barrier(); } while (0)

// ---------------------------------------------------------------------------
// Pack (W + E) -> int8, transposed Bt[n][k] (row stride K bytes).
// ---------------------------------------------------------------------------
__device__ void pack_tile(const int* __restrict__ W, const int* __restrict__ E,
                          char* __restrict__ Bt, int K, int N,
                          int nx, int ky, char* lin) {
  const int t = threadIdx.x;
  const int n0 = nx * 64, k0 = ky * 256;
  {
    const int c  = t & 15;          // column group: 4 ints = 16 B
    const int kq = t >> 4;          // 0..15
    const int ng = n0 + c * 4;
    #pragma unroll 4
    for (int s = 0; s < 16; ++s) {
      const int k = s * 16 + kq;
      const long grow = (long)(k0 + k) * N;
      int a0, a1, a2, a3;
      if (ng + 3 < N) {
        int4 wv = *(const int4*)(W + grow + ng);
        int4 ev = *(const int4*)(E + grow + ng);
        a0 = wv.x + ev.x; a1 = wv.y + ev.y; a2 = wv.z + ev.z; a3 = wv.w + ev.w;
      } else {
        a0 = (ng + 0 < N) ? W[grow + ng + 0] + E[grow + ng + 0] : 0;
        a1 = (ng + 1 < N) ? W[grow + ng + 1] + E[grow + ng + 1] : 0;
        a2 = (ng + 2 < N) ? W[grow + ng + 2] + E[grow + ng + 2] : 0;
        a3 = (ng + 3 < N) ? W[grow + ng + 3] + E[grow + ng + 3] : 0;
      }
      *(int*)(lin + k * 68 + c * 4) = pack4i(a0, a1, a2, a3);
    }
  }
  __syncthreads();
  {
    const int n = t & 63, kq = t >> 6;
    char* dst = Bt + (long)(n0 + n) * K + k0 + (kq << 6);
    int outv[16];
    #pragma unroll
    for (int g = 0; g < 16; ++g) {
      const int k = (kq << 6) + (g << 2);
      outv[g] = pack4i(lin[(k + 0) * 68 + n], lin[(k + 1) * 68 + n],
                       lin[(k + 2) * 68 + n], lin[(k + 3) * 68 + n]);
    }
    #pragma unroll
    for (int g = 0; g < 4; ++g)
      *(int4*)(dst + (g << 4)) =
          make_int4(outv[g * 4], outv[g * 4 + 1], outv[g * 4 + 2], outv[g * 4 + 3]);
  }
}

// ---------------------------------------------------------------------------
// R9 pack_all: weights/bias (bid 0..264) + lane-contiguous X->X8 narrowing
// copy (bid 265..1032; 768 blocks x 32768 ints). R8 accounting showed the
// system is CACHE-BW-bound: gemm1 must consume X as int8 (pre-packed), not
// int32 (8x re-read of 4x the bytes). Copy loads are int4 at t*16 B within
// 1 KB wave-chunks -> every wave-load = 16 fully-used 64 B lines (the R7
// lesson; R2's 64 B/lane-stride variant inflated transactions 4x).
// H is NOT packed: gemm1's epilogue reads it once as int32 (R7-verified).
// ---------------------------------------------------------------------------
__global__ __launch_bounds__(256) void pack_all_kernel(
    const int* W1, const int* E1, char* Bt1,
    const int* W2, const int* E2, char* Bt2,
    const int* W3, const int* E3, char* Bt3,
    const int* b1, const int* eb1, int* bs1,
    const int* b2, const int* eb2, int* bs2,
    const int* b3, const int* eb3, int* bs3,
    const int* X, char* X8) {
  __shared__ __align__(16) char smem[17408];
  const int bid = blockIdx.x;
  if (bid < 192) {
    pack_tile(W1, E1, Bt1, 3072, 1024, bid % 16, bid / 16, smem);
  } else if (bid < 256) {
    const int l = bid - 192;
    pack_tile(W2, E2, Bt2, 1024, 1024, l % 16, l / 16, smem);
  } else if (bid < 264) {
    const int l = bid - 256;
    pack_tile(W3, E3, Bt3, 1024, 100, l & 1, l >> 1, smem);
  } else if (bid == 264) {
    const int t = threadIdx.x;
    for (int i = t; i < 1024; i += 256) {
      bs1[i] = b1[i] + eb1[i];
      bs2[i] = b2[i] + eb2[i];
    }
    for (int i = t; i < 128; i += 256)
      bs3[i] = (i < 100) ? (b3[i] + eb3[i]) : 0;
  } else {
    // X: 25,165,824 ints = 768 blocks x 32768 ints (128 KB in, 32 KB out)
    const int t = threadIdx.x;
    const long base = (long)(bid - 265) * 32768;
    #pragma unroll 2
    for (int it = 0; it < 8; ++it) {
      const long o = base + it * 4096 + t * 4;
      int4 a = *(const int4*)(X + o);
      int4 b = *(const int4*)(X + o + 1024);
      int4 c = *(const int4*)(X + o + 2048);
      int4 d = *(const int4*)(X + o + 3072);
      *(int*)(X8 + o)        = pack4i(a.x, a.y, a.z, a.w);
      *(int*)(X8 + o + 1024) = pack4i(b.x, b.y, b.z, b.w);
      *(int*)(X8 + o + 2048) = pack4i(c.x, c.y, c.z, c.w);
      *(int*)(X8 + o + 3072) = pack4i(d.x, d.y, d.z, d.w);
    }
  }
}

// ---------------------------------------------------------------------------
// R9 gemm1: the R7-VERIFIED gemm2 template (128x128, BK=64, 256 thr, 3-stage
// LDS, depth-2 named-reg prefetch, WAITV(4), 80 B LDS stride) at K=3072 with
// int8 A = X8. Per-CU per-step cache bytes drop 80 KB -> 32 KB (the R8
// accounting: we are L2/L3-BW-bound, int32 A was 4x the bytes re-read 8x).
// Epilogue: R7 gemm1's verified stride-136 transpose + SWAR-add trunc8(H).
// NO structural changes vs the two verified pieces (R8 lesson: restructures
// spill to scratch; watch WRITE_SIZE ~9 MB as the no-spill signature).
// ---------------------------------------------------------------------------
__global__ __launch_bounds__(256, 2) void gemm1_kernel(
    const char* __restrict__ A, const char* __restrict__ Btg,
    const int* __restrict__ bsum, const int* __restrict__ H,
    char* __restrict__ A8out) {
  constexpr int K = 3072, KIT = 48;
  __shared__ __align__(16) char smem[61440];
  const int t = threadIdx.x;
  const int bid = blockIdx.x;
  const int mt = bid & 63, nt = bid >> 6;
  const long m0 = (long)mt << 7;
  const int n0 = nt << 7;

  const int lane = t & 63, w = t >> 6;
  const int lc = lane & 31, hg = lane >> 5;
  const int wm = w >> 1, wn = w & 1;

  v16i acc[2][2] = {};

  const int r = t >> 2, q = t & 3;
  const char* Ar0 = A + (m0 + r) * (long)K + q * 16;
  const char* Ar1 = Ar0 + (long)64 * K;
  const char* Br0 = Btg + (long)(n0 + r) * K + q * 16;
  const char* Br1 = Br0 + (long)64 * K;
  const int awo = r * 80 + q * 16;
  const int bwo = 10240 + r * 80 + q * 16;

  const int fa = (wm * 64 + lc) * 80;
  const int fb = 10240 + (wn * 64 + lc) * 80;

  int4 xA0, xA1, xB0, xB1, yA0, yA1, yB0, yB1;

  auto ISSUEX = [&](int kt) {
    const int ko = kt * 64;
    xA0 = *(const int4*)(Ar0 + ko);
    xA1 = *(const int4*)(Ar1 + ko);
    xB0 = *(const int4*)(Br0 + ko);
    xB1 = *(const int4*)(Br1 + ko);
  };
  auto ISSUEY = [&](int kt) {
    const int ko = kt * 64;
    yA0 = *(const int4*)(Ar0 + ko);
    yA1 = *(const int4*)(Ar1 + ko);
    yB0 = *(const int4*)(Br0 + ko);
    yB1 = *(const int4*)(Br1 + ko);
  };
  auto WRITEX = [&](int st) {
    char* base = smem + st * 20480;
    *(int4*)(base + awo)           = xA0;
    *(int4*)(base + awo + 64 * 80) = xA1;
    *(int4*)(base + bwo)           = xB0;
    *(int4*)(base + bwo + 64 * 80) = xB1;
  };
  auto WRITEY = [&](int st) {
    char* base = smem + st * 20480;
    *(int4*)(base + awo)           = yA0;
    *(int4*)(base + awo + 64 * 80) = yA1;
    *(int4*)(base + bwo)           = yB0;
    *(int4*)(base + bwo + 64 * 80) = yB1;
  };
  auto MSTEP = [&](int st) {
    const char* base = smem + st * 20480;
    __builtin_amdgcn_s_setprio(1);
    #pragma unroll
    for (int ks = 0; ks < 2; ++ks) {
      const int sel = ks * 32 + hg * 16;
      v4i a0 = *(const v4i*)(base + fa + sel);
      v4i a1 = *(const v4i*)(base + fa + 32 * 80 + sel);
      v4i b0 = *(const v4i*)(base + fb + sel);
      v4i b1 = *(const v4i*)(base + fb + 32 * 80 + sel);
      acc[0][0] = MFMA_I8(a0, b0, acc[0][0]);
      acc[0][1] = MFMA_I8(a0, b1, acc[0][1]);
      acc[1][0] = MFMA_I8(a1, b0, acc[1][0]);
      acc[1][1] = MFMA_I8(a1, b1, acc[1][1]);
    }
    __builtin_amdgcn_s_setprio(0);
  };

  ISSUEX(0);
  ISSUEY(1);
  WAITV(4);
  WRITEX(0);
  BARX;
  for (int kt = 0; kt < KIT - 2; kt += 2) {
    ISSUEX(kt + 2);
    MSTEP(kt % 3);
    WAITV(4);
    WRITEY((kt + 1) % 3);
    BARX;
    ISSUEY(kt + 3);
    MSTEP((kt + 1) % 3);
    WAITV(4);
    WRITEX((kt + 2) % 3);
    BARX;
  }
  MSTEP((KIT - 2) % 3);
  WAITV(0);
  WRITEY((KIT - 1) % 3);
  BARX;
  MSTEP((KIT - 1) % 3);

  // Epilogue (R7-verified): LDS transpose stride 136 + SWAR-add trunc8(H).
  BARX;
  const int bsv0 = bsum[n0 + wn * 64 + lc];
  const int bsv1 = bsum[n0 + wn * 64 + 32 + lc];
  #pragma unroll
  for (int i = 0; i < 2; ++i) {
    #pragma unroll
    for (int j = 0; j < 2; ++j) {
      const int bv = j ? bsv1 : bsv0;
      const int col = wn * 64 + j * 32 + lc;
      #pragma unroll
      for (int rr = 0; rr < 16; ++rr) {
        const int row = wm * 64 + i * 32 + (hg << 2) + (rr & 3) + ((rr >> 2) << 3);
        smem[row * 136 + col] = (char)(acc[i][j][rr] + bv);
      }
    }
  }
  BARX;
  const char* srcp = smem + (t >> 1) * 136 + (t & 1) * 64;
  const long gco = (m0 + (t >> 1)) * 1024 + n0 + (t & 1) * 64;
  const int* hp = H + gco;
  #pragma unroll
  for (int g = 0; g < 4; ++g) {
    int4 s  = *(const int4*)(srcp + g * 16);
    int4 h0 = *(const int4*)(hp + g * 16);
    int4 h1 = *(const int4*)(hp + g * 16 + 4);
    int4 h2 = *(const int4*)(hp + g * 16 + 8);
    int4 h3 = *(const int4*)(hp + g * 16 + 12);
    s = make_int4(badd4(s.x, pack4i(h0.x, h0.y, h0.z, h0.w)),
                  badd4(s.y, pack4i(h1.x, h1.y, h1.z, h1.w)),
                  badd4(s.z, pack4i(h2.x, h2.y, h2.z, h2.w)),
                  badd4(s.w, pack4i(h3.x, h3.y, h3.z, h3.w)));
    *(int4*)(A8out + gco + g * 16) = s;
  }
}

// ---------------------------------------------------------------------------
// R9 gemm2: R7 version verbatim (verified; R8's variant is reverted).
// ---------------------------------------------------------------------------
__global__ __launch_bounds__(256, 2) void gemm2_kernel(
    const char* __restrict__ A, const char* __restrict__ Btg,
    const int* __restrict__ bsum, int* __restrict__ Iout) {
  constexpr int K = 1024, KIT = 16;
  __shared__ __align__(16) char smem[61440];
  const int t = threadIdx.x;
  const int bid = blockIdx.x;
  const int mt = bid & 63, nt = bid >> 6;
  const long m0 = (long)mt << 7;
  const int n0 = nt << 7;

  const int lane = t & 63, w = t >> 6;
  const int lc = lane & 31, hg = lane >> 5;
  const int wm = w >> 1, wn = w & 1;

  v16i acc[2][2] = {};

  const int r = t >> 2, q = t & 3;
  const char* Ar0 = A + (m0 + r) * (long)K + q * 16;
  const char* Ar1 = Ar0 + (long)64 * K;
  const char* Br0 = Btg + (long)(n0 + r) * K + q * 16;
  const char* Br1 = Br0 + (long)64 * K;
  const int awo = r * 80 + q * 16;
  const int bwo = 10240 + r * 80 + q * 16;

  const int fa = (wm * 64 + lc) * 80;
  const int fb = 10240 + (wn * 64 + lc) * 80;

  int4 xA0, xA1, xB0, xB1, yA0, yA1, yB0, yB1;

  auto ISSUEX = [&](int kt) {
    const int ko = kt * 64;
    xA0 = *(const int4*)(Ar0 + ko);
    xA1 = *(const int4*)(Ar1 + ko);
    xB0 = *(const int4*)(Br0 + ko);
    xB1 = *(const int4*)(Br1 + ko);
  };
  auto ISSUEY = [&](int kt) {
    const int ko = kt * 64;
    yA0 = *(const int4*)(Ar0 + ko);
    yA1 = *(const int4*)(Ar1 + ko);
    yB0 = *(const int4*)(Br0 + ko);
    yB1 = *(const int4*)(Br1 + ko);
  };
  auto WRITEX = [&](int st) {
    char* base = smem + st * 20480;
    *(int4*)(base + awo)           = xA0;
    *(int4*)(base + awo + 64 * 80) = xA1;
    *(int4*)(base + bwo)           = xB0;
    *(int4*)(base + bwo + 64 * 80) = xB1;
  };
  auto WRITEY = [&](int st) {
    char* base = smem + st * 20480;
    *(int4*)(base + awo)           = yA0;
    *(int4*)(base + awo + 64 * 80) = yA1;
    *(int4*)(base + bwo)           = yB0;
    *(int4*)(base + bwo + 64 * 80) = yB1;
  };
  auto MSTEP = [&](int st) {
    const char* base = smem + st * 20480;
    __builtin_amdgcn_s_setprio(1);
    #pragma unroll
    for (int ks = 0; ks < 2; ++ks) {
      const int sel = ks * 32 + hg * 16;
      v4i a0 = *(const v4i*)(base + fa + sel);
      v4i a1 = *(const v4i*)(base + fa + 32 * 80 + sel);
      v4i b0 = *(const v4i*)(base + fb + sel);
      v4i b1 = *(const v4i*)(base + fb + 32 * 80 + sel);
      acc[0][0] = MFMA_I8(a0, b0, acc[0][0]);
      acc[0][1] = MFMA_I8(a0, b1, acc[0][1]);
      acc[1][0] = MFMA_I8(a1, b0, acc[1][0]);
      acc[1][1] = MFMA_I8(a1, b1, acc[1][1]);
    }
    __builtin_amdgcn_s_setprio(0);
  };

  ISSUEX(0);
  ISSUEY(1);
  WAITV(4);
  WRITEX(0);
  BARX;
  for (int kt = 0; kt < KIT - 2; kt += 2) {
    ISSUEX(kt + 2);
    MSTEP(kt % 3);
    WAITV(4);
    WRITEY((kt + 1) % 3);
    BARX;
    ISSUEY(kt + 3);
    MSTEP((kt + 1) % 3);
    WAITV(4);
    WRITEX((kt + 2) % 3);
    BARX;
  }
  MSTEP((KIT - 2) % 3);
  WAITV(0);
  WRITEY((KIT - 1) % 3);
  BARX;
  MSTEP((KIT - 1) % 3);

  const int bsj0 = bsum[n0 + wn * 64 + lc];
  const int bsj1 = bsum[n0 + wn * 64 + 32 + lc];
  #pragma unroll
  for (int i = 0; i < 2; ++i) {
    #pragma unroll
    for (int j = 0; j < 2; ++j) {
      const int bv = j ? bsj1 : bsj0;
      const int col = n0 + wn * 64 + j * 32 + lc;
      #pragma unroll
      for (int rr = 0; rr < 16; ++rr) {
        const long row = m0 + wm * 64 + i * 32 + (hg << 2) + (rr & 3) + ((rr >> 2) << 3);
        Iout[row * 1024 + col] = (int)(signed char)(acc[i][j][rr] + bv);
      }
    }
  }
}

// ---------------------------------------------------------------------------
// Layer 3: 16x128 tile, 512 blocks (2/CU), mfma_i32_16x16x64_i8, 2-stage.
// A = h2 int32 from d_out, packed to int8 in staging. (Long-verified.)
// ---------------------------------------------------------------------------
__global__ __launch_bounds__(256, 2) void gemm3_kernel(
    const int* __restrict__ h2, const char* __restrict__ Btg,
    const int* __restrict__ bsum, int* __restrict__ Iout) {
  // stage: As 16x80 (1280) + Bs 128x80 (10240) = 11520; x2 = 23040
  __shared__ __align__(16) char smem[23040];
  const int t = threadIdx.x;
  const int m0 = blockIdx.x << 4;
  const int lane = t & 63, w = t >> 6;
  const int l16 = lane & 15, q = lane >> 4;
  v4i acc0 = {}, acc1 = {};

  const int am = t >> 4, ah = t & 15;      // 16 rows x 16 thr x 4 ints
  const int* Arow = h2 + (long)(m0 + am) * 1024 + ah * 4;
  const int aoff = am * 80 + ah * 4;
  const int bm = t >> 1, bh = t & 1;       // 128 rows x 2 thr x 32 B
  const char* Brow = Btg + (long)bm * 1024 + bh * 32;
  const int boff = bm * 80 + bh * 32;

  const int abo  = l16 * 80 + q * 16;
  const int bbo0 = (w * 32 + l16) * 80 + q * 16;
  const int bbo1 = (w * 32 + 16 + l16) * 80 + q * 16;

  int4 ar, br0, br1;
  auto LOAD = [&](int kt) {
    const int kb = kt << 6;
    ar  = *(const int4*)(Arow + kb);
    br0 = *(const int4*)(Brow + kb);
    br1 = *(const int4*)(Brow + kb + 16);
  };
  auto STORE = [&](int stage) {
    char* base = smem + stage * 11520;
    *(int*)(base + aoff) = pack4i(ar.x, ar.y, ar.z, ar.w);
    *(int4*)(base + 1280 + boff)      = br0;
    *(int4*)(base + 1280 + boff + 16) = br1;
  };
  auto MFMA = [&](int stage) {
    const char* base = smem + stage * 11520;
    v4i a  = *(const v4i*)(base + abo);
    v4i b0 = *(const v4i*)(base + 1280 + bbo0);
    v4i b1 = *(const v4i*)(base + 1280 + bbo1);
    acc0 = __builtin_amdgcn_mfma_i32_16x16x64_i8(a, b0, acc0, 0, 0, 0);
    acc1 = __builtin_amdgcn_mfma_i32_16x16x64_i8(a, b1, acc1, 0, 0, 0);
  };

  LOAD(0); STORE(0); __syncthreads();
  for (int kt = 0; kt < 16; ++kt) {
    if (kt + 1 < 16) LOAD(kt + 1);
    MFMA(kt & 1);
    if (kt + 1 < 16) { STORE((kt + 1) & 1); __syncthreads(); }
  }

  const int c0 = w * 32 + l16;       // cols {0-15,32-47,64-79,96-111}
  const int c1 = c0 + 16;            // cols {16-31,48-63,80-95,112-127}
  if (c0 < 100) {
    const int b = bsum[c0];
    #pragma unroll
    for (int rr = 0; rr < 4; ++rr)
      Iout[(long)(m0 + q * 4 + rr) * 100 + c0] = (int)(signed char)(acc0[rr] + b);
  }
  if (c1 < 100) {
    const int b = bsum[c1];
    #pragma unroll
    for (int rr = 0; rr < 4; ++rr)
      Iout[(long)(m0 + q * 4 + rr) * 100 + c1] = (int)(signed char)(acc1[rr] + b);
  }
}

// ---------------------------------------------------------------------------
// ws (12.7 MB): Bt1 | Bt2 | Bt3 | bs1 | bs2 | bs3 | A2
// d_out scratch: X8 [0, 25.2 MB) — dead before gemm2 overwrites the region
// with h2 (launch order on one stream guarantees it; R0-proven pattern).
// ---------------------------------------------------------------------------
extern "C" void kernel_launch(void* const* d_in, const int* in_sizes, int n_in,
                              void* d_out, int out_size, void* d_ws, size_t ws_size,
                              hipStream_t stream) {
  (void)in_sizes; (void)n_in; (void)out_size; (void)ws_size;
  const int* W1  = (const int*)d_in[0];
  const int* b1  = (const int*)d_in[1];
  const int* W2  = (const int*)d_in[2];
  const int* b2  = (const int*)d_in[3];
  const int* W3  = (const int*)d_in[4];
  const int* b3  = (const int*)d_in[5];
  const int* E1  = (const int*)d_in[6];
  const int* eb1 = (const int*)d_in[7];
  const int* E2  = (const int*)d_in[8];
  const int* eb2 = (const int*)d_in[9];
  const int* E3  = (const int*)d_in[10];
  const int* eb3 = (const int*)d_in[11];
  const int* X   = (const int*)d_in[12];   // [8192][3072] int32
  const int* H   = (const int*)d_in[13];   // [8192][1024] int32
  int* out = (int*)d_out;                  // h2 [8192*1024] then out [8192*100]

  char* ws  = (char*)d_ws;
  char* Bt1 = ws;                          // 3,145,728
  char* Bt2 = Bt1 + 3145728;               // 1,048,576
  char* Bt3 = Bt2 + 1048576;               //   131,072 (rows 100..127 zeroed)
  int*  bs1 = (int*)(Bt3 + 131072);        // 1024 ints
  int*  bs2 = bs1 + 1024;                  // 1024 ints
  int*  bs3 = bs2 + 1024;                  //  128 ints
  char* A2  = (char*)(bs3 + 128);          // 8,388,608 int8
  char* X8  = (char*)d_out;                // 25,165,824 int8 (temp in d_out)

  pack_all_kernel<<<dim3(1033), dim3(256), 0, stream>>>(
      W1, E1, Bt1, W2, E2, Bt2, W3, E3, Bt3,
      b1, eb1, bs1, b2, eb2, bs2, b3, eb3, bs3, X, X8);

  // Layer 1: X8 (int8) -> i2c ; epilogue adds trunc8(H int32) -> A2
  gemm1_kernel<<<dim3(512), dim3(256), 0, stream>>>(X8, Bt1, bs1, H, A2);

  // Layer 2: h2 -> d_out (int32)
  gemm2_kernel<<<dim3(512), dim3(256), 0, stream>>>(A2, Bt2, bs2, out);

  // Layer 3: reads h2 from d_out (int32), writes out region (int32)
  gemm3_kernel<<<dim3(512), dim3(256), 0, stream>>>(
      out, Bt3, bs3, out + 8388608);
}